// Round 1
// baseline (170.751 us; speedup 1.0000x reference)
//
#include <hip/hip_runtime.h>

#define NQ 14
#define NSTATE (1 << NQ)   // 16384 amplitudes (real)
#define NPAIR (NSTATE / 2)
#define NGATES 28          // 2 layers x 14 parameterized RY
#define BLOCK 256

// Precomputed (host-side) lazy-CNOT schedule: for each RY gate, the XOR mask
// m of its pair partner in stored-index space and the parity mask r that
// identifies the |0> element of each pair; fr[] are final measurement parity
// masks for <Z_w>.
struct Sched {
  unsigned short m[NGATES];
  unsigned short r[NGATES];
  unsigned short fr[NQ];
};

__global__ __launch_bounds__(BLOCK, 2) void qnn_kernel(
    const float* __restrict__ x, const float* __restrict__ weights,
    float* __restrict__ out, Sched sc) {
  __shared__ float S[NSTATE];  // 64 KB: full state vector for this batch elem
  const int b = blockIdx.x;
  const int tid = threadIdx.x;

  // Data-encoding angles for this batch element
  float c[NQ], s[NQ];
#pragma unroll
  for (int w = 0; w < NQ; ++w) {
    const float th = 0.5f * x[b * NQ + w];
    c[w] = cosf(th);
    s[w] = sinf(th);
  }

  // Product-state init: RY layer applied to |0...0> gives
  // S[i] = prod_w (bit_w(i) ? sin : cos). Wire w is bit (NQ-1-w).
  for (int i = tid; i < NSTATE; i += BLOCK) {
    float p = 1.0f;
#pragma unroll
    for (int w = 0; w < NQ; ++w) {
      p *= ((i >> (NQ - 1 - w)) & 1) ? s[w] : c[w];
    }
    S[i] = p;
  }
  __syncthreads();

  // 28 weight RY gates; CNOTs folded into the (m, r) masks.
  for (int g = 0; g < NGATES; ++g) {
    const float th = 0.5f * weights[g];
    const float cg = cosf(th);
    const float sg = sinf(th);
    const unsigned m = sc.m[g];
    const unsigned r = sc.r[g];
    const unsigned pivot = m & (0u - m);  // lowest set bit of m
    const unsigned low = pivot - 1u;
    for (int t = tid; t < NPAIR; t += BLOCK) {
      // expand t (13 bits) to 14-bit index with pivot bit = 0
      const unsigned i = ((((unsigned)t) & ~low) << 1) | (((unsigned)t) & low);
      const unsigned j = i ^ m;
      // parity(r & i) == 0  <=>  i holds the a0 (bit=0) element
      const unsigned par = (unsigned)__popc(i & r) & 1u;
      // uniform update: flip sign of s when roles are swapped
      const float ss = __int_as_float(__float_as_int(sg) ^ (par << 31));
      const float ai = S[i];
      const float aj = S[j];
      S[i] = cg * ai - ss * aj;
      S[j] = ss * ai + cg * aj;
    }
    __syncthreads();
  }

  // Expectation values <Z_w> = sum_i S[i]^2 * (1 - 2*parity(fr[w] & i))
  float acc[NQ];
#pragma unroll
  for (int w = 0; w < NQ; ++w) acc[w] = 0.0f;
  for (int i = tid; i < NSTATE; i += BLOCK) {
    const float v = S[i];
    const float p = v * v;
#pragma unroll
    for (int w = 0; w < NQ; ++w) {
      const unsigned par = (unsigned)__popc(i & (unsigned)sc.fr[w]) & 1u;
      acc[w] += __int_as_float(__float_as_int(p) ^ (par << 31));
    }
  }
  __syncthreads();  // all reads of S done; safe to reuse for reduction

  // wave (64-lane) shuffle reduction, then combine 4 waves via LDS
  const int lane = tid & 63;
  const int wave = tid >> 6;
#pragma unroll
  for (int w = 0; w < NQ; ++w) {
#pragma unroll
    for (int off = 32; off > 0; off >>= 1) acc[w] += __shfl_down(acc[w], off);
  }
  if (lane == 0) {
#pragma unroll
    for (int w = 0; w < NQ; ++w) S[wave * NQ + w] = acc[w];
  }
  __syncthreads();
  if (tid < NQ) {
    out[b * NQ + tid] = S[tid] + S[NQ + tid] + S[2 * NQ + tid] + S[3 * NQ + tid];
  }
}

// Build the lazy-CNOT schedule on the host (circuit structure is fixed).
// We maintain M (columns col[p]) with stored index i = M * j (j = true index),
// and M^{-1} (rows rowinv[p]). Applying CNOT(ctrl bit pc -> tgt bit pt):
//   M' = M*C      => col[pc] ^= col[pt]
//   M'^{-1} = C*M^{-1} => rowinv[pt] ^= rowinv[pc]
static Sched build_sched() {
  const int n = NQ, L = 2;
  unsigned col[NQ], rowinv[NQ];
  for (int p = 0; p < n; ++p) {
    col[p] = 1u << p;
    rowinv[p] = 1u << p;
  }
  Sched sc;
  int g = 0;
  for (int l = 0; l < L; ++l) {
    for (int w = 0; w < n; ++w) {  // RY(weights[l,w], w) under current M
      const int p = n - 1 - w;
      sc.m[g] = (unsigned short)col[p];
      sc.r[g] = (unsigned short)rowinv[p];
      ++g;
    }
    for (int w = 0; w < n; ++w) {  // CNOT(w, (w+1)%n)
      const int tgt = (w + 1) % n;
      const int pc = n - 1 - w;
      const int pt = n - 1 - tgt;
      col[pc] ^= col[pt];
      rowinv[pt] ^= rowinv[pc];
    }
  }
  for (int w = 0; w < n; ++w) sc.fr[w] = (unsigned short)rowinv[n - 1 - w];
  return sc;
}

extern "C" void kernel_launch(void* const* d_in, const int* in_sizes, int n_in,
                              void* d_out, int out_size, void* d_ws, size_t ws_size,
                              hipStream_t stream) {
  const float* x = (const float*)d_in[0];        // (B, 14) fp32
  const float* weights = (const float*)d_in[1];  // (2, 14) fp32
  float* out = (float*)d_out;                    // (B, 14) fp32
  const int B = in_sizes[0] / NQ;
  const Sched sc = build_sched();
  qnn_kernel<<<B, BLOCK, 0, stream>>>(x, weights, out, sc);
}

// Round 2
// 71.686 us; speedup vs baseline: 2.3819x; 2.3819x over previous
//
#include <hip/hip_runtime.h>

#define NQ 14
#define NSTATE (1 << NQ)
#define BLOCK 256
#define NG 28

// ---------------- compile-time schedule (lazy-CNOT folding) ----------------
struct Sched { unsigned m[NG]; unsigned r[NG]; unsigned fr[NQ]; };

constexpr Sched build_sched() {
  Sched sc{};
  unsigned col[NQ] = {}, rowinv[NQ] = {};
  for (int p = 0; p < NQ; ++p) { col[p] = 1u << p; rowinv[p] = 1u << p; }
  int g = 0;
  for (int l = 0; l < 2; ++l) {
    for (int w = 0; w < NQ; ++w) { int p = NQ - 1 - w; sc.m[g] = col[p]; sc.r[g] = rowinv[p]; ++g; }
    for (int w = 0; w < NQ; ++w) {
      int tgt = (w + 1) % NQ; int pc = NQ - 1 - w, pt = NQ - 1 - tgt;
      col[pc] ^= col[pt]; rowinv[pt] ^= rowinv[pc];
    }
  }
  for (int w = 0; w < NQ; ++w) sc.fr[w] = rowinv[NQ - 1 - w];
  return sc;
}
constexpr Sched SC = build_sched();

// Phase gate lists (indices into SC). Order = execution order.
// QA: local bits {8..13}; QB: local {3..8}; QC: local {0,1,2,3,12,13}.
constexpr int QA_G[10] = {0, 1, 2, 3, 4, 5, 15, 16, 17, 18};
constexpr int QB_G[10] = {6, 7, 8, 9, 10, 19, 20, 21, 22, 23};
constexpr int QC_G[8]  = {11, 12, 13, 14, 24, 25, 26, 27};

// mask -> 6-bit local-coordinate maps per phase (local dirs are single bits)
constexpr unsigned lmapA(unsigned v) { return (v >> 8) & 63u; }
constexpr unsigned lmapB(unsigned v) { return (v >> 3) & 63u; }
constexpr unsigned lmapC(unsigned v) { return (v & 0xFu) | ((v >> 8) & 0x30u); }

// Machine-check: (1) each phase's gate masks fit its local subspace,
// (2) parity(mu&rho)==1, (3) any out-of-original-order pair commutes:
// G_a,G_b commute iff parity(r_a&m_b)==parity(r_b&m_a).
constexpr bool sched_ok() {
  const unsigned spanA = 0x3F00u, spanB = 0x01F8u, spanC = 0x300Fu;
  for (int k = 0; k < 10; ++k) {
    if (SC.m[QA_G[k]] & ~spanA) return false;
    if (!(__builtin_popcount(lmapA(SC.m[QA_G[k]]) & lmapA(SC.r[QA_G[k]])) & 1)) return false;
  }
  for (int k = 0; k < 10; ++k) {
    if (SC.m[QB_G[k]] & ~spanB) return false;
    if (!(__builtin_popcount(lmapB(SC.m[QB_G[k]]) & lmapB(SC.r[QB_G[k]])) & 1)) return false;
  }
  for (int k = 0; k < 8; ++k) {
    if (SC.m[QC_G[k]] & ~spanC) return false;
    if (!(__builtin_popcount(lmapC(SC.m[QC_G[k]]) & lmapC(SC.r[QC_G[k]])) & 1)) return false;
  }
  // execution order
  int ord[NG] = {};
  int n = 0;
  for (int k = 0; k < 10; ++k) ord[n++] = QA_G[k];
  for (int k = 0; k < 10; ++k) ord[n++] = QB_G[k];
  for (int k = 0; k < 8;  ++k) ord[n++] = QC_G[k];
  // every gate exactly once
  for (int g = 0; g < NG; ++g) {
    int cnt = 0;
    for (int i = 0; i < NG; ++i) if (ord[i] == g) ++cnt;
    if (cnt != 1) return false;
  }
  for (int i = 0; i < NG; ++i)
    for (int j = i + 1; j < NG; ++j)
      if (ord[i] > ord[j]) {  // swapped vs original order -> must commute
        int a = ord[i], b = ord[j];
        int pab = __builtin_popcount(SC.r[a] & SC.m[b]) & 1;
        int pba = __builtin_popcount(SC.r[b] & SC.m[a]) & 1;
        if (pab != pba) return false;
      }
  return true;
}
static_assert(sched_ok(), "schedule invalid");

// LDS bank swizzle: addr = i ^ ((i>>6)&31). GF(2)-linear, rank-5 lane->bank
// for all four access patterns (QA write / QB read / QB write / QC read).
__host__ __device__ constexpr unsigned swz(unsigned i) { return i ^ ((i >> 6) & 0x1Fu); }

// Register butterfly for one gate with compile-time local mask MU / parity RHO.
template <unsigned MU, unsigned RHO>
__device__ __forceinline__ void gate(float* v, float cg, float sg, int tpar) {
  const float sb = tpar ? -sg : sg;
  constexpr unsigned LSB = MU & (0u - MU);
#pragma unroll
  for (unsigned l0 = 0; l0 < 64; ++l0) {
    if (l0 & LSB) continue;
    const unsigned l1 = l0 ^ MU;
    const bool sw = (__builtin_popcount(l0 & RHO) & 1) != 0;
    const unsigned A = sw ? l1 : l0;
    const unsigned B = sw ? l0 : l1;
    const float a = v[A], b = v[B];
    v[A] = fmaf(cg, a, -(sb * b));
    v[B] = fmaf(cg, b, (sb * a));
  }
}

__global__ __launch_bounds__(BLOCK, 2) void qnn_kernel(
    const float* __restrict__ x, const float* __restrict__ wts,
    float* __restrict__ out) {
  __shared__ float S[NSTATE];  // 64 KB
  const int b = blockIdx.x;
  const unsigned tid = threadIdx.x;

  float v[64];

  // ---- Fill (x-encoding RY layer on |0..0> = product state), QA layout ----
  // QA: i = tid (bits 0-7) | l<<8 (bits 8-13). wire w <-> bit 13-w.
  {
    float cx[NQ], sx[NQ];
#pragma unroll
    for (int w = 0; w < NQ; ++w) __sincosf(0.5f * x[b * NQ + w], &sx[w], &cx[w]);
    float pl = 1.0f;
#pragma unroll
    for (int bb = 0; bb < 8; ++bb) pl *= ((tid >> bb) & 1) ? sx[13 - bb] : cx[13 - bb];
    v[0] = pl;
#pragma unroll
    for (int k = 0; k < 6; ++k) {  // l bit k <-> i bit 8+k <-> wire 5-k
      const float sk = sx[5 - k], ck = cx[5 - k];
#pragma unroll
      for (int l = (1 << k) - 1; l >= 0; --l) {
        v[l | (1 << k)] = v[l] * sk;
        v[l] = v[l] * ck;
      }
    }
  }

#define RUN_GATE(LM, G, BASE)                                             \
  {                                                                       \
    float sn, cs;                                                         \
    __sincosf(0.5f * wts[G], &sn, &cs);                                   \
    const int tp = __builtin_popcount((BASE) & SC.r[G]) & 1;              \
    gate<LM(SC.m[G]), LM(SC.r[G])>(v, cs, sn, tp);                        \
  }

  // ---------------- Phase QA: local bits {8..13} ----------------
  {
    const unsigned base = tid;  // i bits 0-7
    RUN_GATE(lmapA, QA_G[0], base) RUN_GATE(lmapA, QA_G[1], base)
    RUN_GATE(lmapA, QA_G[2], base) RUN_GATE(lmapA, QA_G[3], base)
    RUN_GATE(lmapA, QA_G[4], base) RUN_GATE(lmapA, QA_G[5], base)
    RUN_GATE(lmapA, QA_G[6], base) RUN_GATE(lmapA, QA_G[7], base)
    RUN_GATE(lmapA, QA_G[8], base) RUN_GATE(lmapA, QA_G[9], base)
    // write to LDS
    const unsigned wa = swz(tid);
#pragma unroll
    for (unsigned l = 0; l < 64; ++l) S[wa ^ swz(l << 8)] = v[l];
  }
  __syncthreads();

  // ---------------- Phase QB: local bits {3..8} ----------------
  {
    const unsigned base = (tid & 7u) | (((tid >> 3) & 0x1Fu) << 9);  // i bits {0,1,2,9..13}
    const unsigned ra = swz(base);
#pragma unroll
    for (unsigned l = 0; l < 64; ++l) v[l] = S[ra ^ swz(l << 3)];
    RUN_GATE(lmapB, QB_G[0], base) RUN_GATE(lmapB, QB_G[1], base)
    RUN_GATE(lmapB, QB_G[2], base) RUN_GATE(lmapB, QB_G[3], base)
    RUN_GATE(lmapB, QB_G[4], base) RUN_GATE(lmapB, QB_G[5], base)
    RUN_GATE(lmapB, QB_G[6], base) RUN_GATE(lmapB, QB_G[7], base)
    RUN_GATE(lmapB, QB_G[8], base) RUN_GATE(lmapB, QB_G[9], base)
    // write back to the SAME addresses this thread read (disjoint per thread)
#pragma unroll
    for (unsigned l = 0; l < 64; ++l) S[ra ^ swz(l << 3)] = v[l];
  }
  __syncthreads();

  // ---------------- Phase QC: local bits {0,1,2,3,12,13} ----------------
  float ex[NQ];
  {
    const unsigned base = tid << 4;  // i bits 4-11
    const unsigned rc = swz(base);
#pragma unroll
    for (unsigned l = 0; l < 64; ++l) {
      const unsigned off = (l & 0xFu) | ((l >> 4) << 12);
      v[l] = S[rc ^ swz(off)];
    }
    __syncthreads();  // all QC reads done before S is reused for reduction
    RUN_GATE(lmapC, QC_G[0], base) RUN_GATE(lmapC, QC_G[1], base)
    RUN_GATE(lmapC, QC_G[2], base) RUN_GATE(lmapC, QC_G[3], base)
    RUN_GATE(lmapC, QC_G[4], base) RUN_GATE(lmapC, QC_G[5], base)
    RUN_GATE(lmapC, QC_G[6], base) RUN_GATE(lmapC, QC_G[7], base)

    // ---- Measurement: q = v^2, 64-pt WHT, pick coefficient per wire ----
#pragma unroll
    for (int l = 0; l < 64; ++l) v[l] *= v[l];
#pragma unroll
    for (int k = 0; k < 6; ++k) {
#pragma unroll
      for (int l = 0; l < 64; ++l) {
        if (l & (1 << k)) continue;
        const float a = v[l], bb2 = v[l ^ (1 << k)];
        v[l] = a + bb2;
        v[l ^ (1 << k)] = a - bb2;
      }
    }
#pragma unroll
    for (int w = 0; w < NQ; ++w) {
      const float coef = v[lmapC(SC.fr[w])];
      const int tf = __builtin_popcount(base & SC.fr[w]) & 1;
      ex[w] = tf ? -coef : coef;
    }
  }

  // ---------------- block reduction ----------------
#pragma unroll
  for (int w = 0; w < NQ; ++w) {
#pragma unroll
    for (int off = 32; off > 0; off >>= 1) ex[w] += __shfl_xor(ex[w], off, 64);
  }
  const int lane = tid & 63, wave = tid >> 6;
  if (lane == 0) {
#pragma unroll
    for (int w = 0; w < NQ; ++w) S[wave * NQ + w] = ex[w];
  }
  __syncthreads();
  if (tid < NQ) {
    out[b * NQ + tid] = S[tid] + S[NQ + tid] + S[2 * NQ + tid] + S[3 * NQ + tid];
  }
#undef RUN_GATE
}

extern "C" void kernel_launch(void* const* d_in, const int* in_sizes, int n_in,
                              void* d_out, int out_size, void* d_ws, size_t ws_size,
                              hipStream_t stream) {
  const float* x = (const float*)d_in[0];        // (B, 14) fp32
  const float* weights = (const float*)d_in[1];  // (2, 14) fp32
  float* out = (float*)d_out;                    // (B, 14) fp32
  const int B = in_sizes[0] / NQ;
  qnn_kernel<<<B, BLOCK, 0, stream>>>(x, weights, out);
}

// Round 4
// 65.332 us; speedup vs baseline: 2.6136x; 1.0973x over previous
//
#include <hip/hip_runtime.h>

#define NQ 14
#define BLOCK 256
#define NG 28

typedef float f32x2 __attribute__((ext_vector_type(2)));
__device__ __forceinline__ f32x2 mk2(float a, float b) { f32x2 r; r.x = a; r.y = b; return r; }

// ---------------- compile-time schedule (lazy-CNOT folding) ----------------
struct Sched { unsigned m[NG]; unsigned r[NG]; unsigned fr[NQ]; };

constexpr Sched build_sched() {
  Sched sc{};
  unsigned col[NQ] = {}, rowinv[NQ] = {};
  for (int p = 0; p < NQ; ++p) { col[p] = 1u << p; rowinv[p] = 1u << p; }
  int g = 0;
  for (int l = 0; l < 2; ++l) {
    for (int w = 0; w < NQ; ++w) { int p = NQ - 1 - w; sc.m[g] = col[p]; sc.r[g] = rowinv[p]; ++g; }
    for (int w = 0; w < NQ; ++w) {
      int tgt = (w + 1) % NQ; int pc = NQ - 1 - w, pt = NQ - 1 - tgt;
      col[pc] ^= col[pt]; rowinv[pt] ^= rowinv[pc];
    }
  }
  for (int w = 0; w < NQ; ++w) sc.fr[w] = rowinv[NQ - 1 - w];
  return sc;
}
constexpr Sched SC = build_sched();

constexpr int QA_G[10] = {0, 1, 2, 3, 4, 5, 15, 16, 17, 18};
constexpr int QB_G[10] = {6, 7, 8, 9, 10, 19, 20, 21, 22, 23};
constexpr int QC_G[8]  = {11, 12, 13, 14, 24, 25, 26, 27};

// local-coordinate maps; local bit 0 == the f32x2 packed lane in each phase
constexpr unsigned lmapA(unsigned v) { return (v >> 8) & 63u; }                              // lane = i8
constexpr unsigned lmapB(unsigned v) { return ((v >> 8) & 1u) | (((v >> 3) & 31u) << 1); }   // lane = i8
constexpr unsigned lmapC(unsigned v) { return (v & 0xFu) | ((v >> 8) & 0x30u); }             // lane = i0

// ---------------- schedule legality (machine-checked) ----------------
constexpr bool sched_ok() {
  const unsigned spanA = 0x3F00u, spanB = 0x01F8u, spanC = 0x300Fu;
  for (int k = 0; k < 10; ++k) {
    if (SC.m[QA_G[k]] & ~spanA) return false;
    if (!(__builtin_popcount(lmapA(SC.m[QA_G[k]]) & lmapA(SC.r[QA_G[k]])) & 1)) return false;
  }
  for (int k = 0; k < 10; ++k) {
    if (SC.m[QB_G[k]] & ~spanB) return false;
    if (!(__builtin_popcount(lmapB(SC.m[QB_G[k]]) & lmapB(SC.r[QB_G[k]])) & 1)) return false;
  }
  for (int k = 0; k < 8; ++k) {
    if (SC.m[QC_G[k]] & ~spanC) return false;
    if (!(__builtin_popcount(lmapC(SC.m[QC_G[k]]) & lmapC(SC.r[QC_G[k]])) & 1)) return false;
  }
  int ord[NG] = {}; int n = 0;
  for (int k = 0; k < 10; ++k) ord[n++] = QA_G[k];
  for (int k = 0; k < 10; ++k) ord[n++] = QB_G[k];
  for (int k = 0; k < 8;  ++k) ord[n++] = QC_G[k];
  for (int g = 0; g < NG; ++g) { int c = 0; for (int i = 0; i < NG; ++i) if (ord[i] == g) ++c; if (c != 1) return false; }
  for (int i = 0; i < NG; ++i)
    for (int j = i + 1; j < NG; ++j)
      if (ord[i] > ord[j]) {
        int a = ord[i], b = ord[j];
        if ((__builtin_popcount(SC.r[a] & SC.m[b]) & 1) != (__builtin_popcount(SC.r[b] & SC.m[a]) & 1)) return false;
      }
  return true;
}
static_assert(sched_ok(), "schedule invalid");

// ---------------- layouts: (thread,reg,lane) -> state index i ----------------
constexpr unsigned iQA(unsigned t, unsigned p, unsigned e) { return t | ((2u * p + e) << 8); }
constexpr unsigned iQB(unsigned t, unsigned p, unsigned e) { return (t & 7u) | (p << 3) | (e << 8) | ((t >> 3) << 9); }
constexpr unsigned iQC(unsigned T, unsigned p, unsigned e) {
  return e | ((p & 7u) << 1) | (((p >> 3) & 3u) << 12) | (((T >> 3) & 15u) << 4) | (((T >> 7) & 1u) << 8) | ((T & 7u) << 9);
}

// canonical storage maps (dword address as a function of state index i)
// storage-1 (QA->QB), storage-2 (QB->QC); one 16384-dword buffer reused
constexpr unsigned a1s(unsigned i) { unsigned tA = i & 255u, lA = i >> 8; return tA * 64u + (lA ^ ((tA & 15u) << 1)); }
constexpr unsigned Tof(unsigned i)  { return ((i >> 9) & 7u) | (((i >> 4) & 15u) << 3) | (((i >> 8) & 1u) << 7); }
constexpr unsigned lCof(unsigned i) { return (i & 15u) | (((i >> 12) & 3u) << 4); }
constexpr unsigned a2s(unsigned i) { unsigned T = Tof(i), l = lCof(i); return T * 64u + (l ^ ((T & 7u) << 2)); }

// ---- device-used address functions. The SAME definitions are evaluated in
// the exhaustive static_asserts below — no device/mirror drift possible. ----
__host__ __device__ constexpr unsigned f2_QAw(unsigned t, unsigned p) {
  return 32u * t + (p ^ (t & 15u));
}
__host__ __device__ constexpr unsigned f2_QBr(unsigned t, unsigned p) {
  return 256u * p + 32u * (t & 7u) + (((t >> 3) ^ (t & 7u)) ^ (8u * (p & 1u)));
}
__host__ __device__ constexpr unsigned dw_QBw(unsigned t, unsigned p, unsigned e) {
  const unsigned lc = (t & 7u) | (8u * (p & 1u)) | (16u * ((t >> 6) & 3u));
  return 64u * ((t >> 3) & 7u) + 512u * (p >> 1) + 8192u * e + (lc ^ (((t >> 3) & 7u) << 2));
}
__host__ __device__ constexpr unsigned f2_QCr(unsigned t, unsigned p) {
  return 32u * t + (p ^ ((t & 7u) << 1));   // swizzle hits p bits 1..3 (l bits 2..4)
}

constexpr bool basis_ok() {
  for (int mapi = 0; mapi < 3; ++mapi) {
    unsigned acc = 0;
    for (int k = 0; k < 14; ++k) {
      unsigned t = 0, p = 0, e = 0;
      if (k < 8) t = 1u << k; else if (k < 13) p = 1u << (k - 8); else e = 1;
      unsigned v = (mapi == 0) ? iQA(t, p, e) : (mapi == 1) ? iQB(t, p, e) : iQC(t, p, e);
      if (__builtin_popcount(v) != 1 || (acc & v)) return false;
      acc |= v;
    }
    if (acc != 0x3FFFu) return false;
  }
  return true;
}
static_assert(basis_ok(), "layout maps not bijective");

// exhaustive: every thread, register, lane; device formula == storage map
constexpr bool chk_addr(int pat, unsigned t0, unsigned t1) {
  for (unsigned t = t0; t < t1; ++t)
    for (unsigned p = 0; p < 32; ++p)
      for (unsigned e = 0; e < 2; ++e) {
        unsigned a = 0, b = 0;
        if (pat == 0) { a = 2u * f2_QAw(t, p) + e; b = a1s(iQA(t, p, e)); }
        if (pat == 1) { a = 2u * f2_QBr(t, p) + e; b = a1s(iQB(t, p, e)); }
        if (pat == 2) { a = dw_QBw(t, p, e);       b = a2s(iQB(t, p, e)); }
        if (pat == 3) { a = 2u * f2_QCr(t, p) + e; b = a2s(iQC(t, p, e)); }
        if (a != b || a >= 16384u) return false;
      }
  return true;
}
static_assert(chk_addr(0, 0, 128) && chk_addr(0, 128, 256), "QA write addr");
static_assert(chk_addr(1, 0, 128) && chk_addr(1, 128, 256), "QB read addr");
static_assert(chk_addr(2, 0, 128) && chk_addr(2, 128, 256), "QB write addr");
static_assert(chk_addr(3, 0, 128) && chk_addr(3, 128, 256), "QC read addr");

// ---------------- packed register butterfly ----------------
// v[l]' = c*v[l] - sigma(l)*sb*v[l^MU], sigma(l) = parity(l&RHO) ? -1 : +1,
// local 6-bit space, lane = bit 0; parity(MU&RHO)==1 asserted by sched_ok.
template <unsigned MU, unsigned RHO>
__device__ __forceinline__ void gate_pk(f32x2* v, const float cg, const float sb) {
  const f32x2 C = mk2(cg, cg);
  constexpr unsigned M2 = MU >> 1;
  constexpr bool ODD = (MU & 1u) != 0;
  if constexpr (!ODD) {
    constexpr unsigned LSB = M2 & (0u - M2);
#pragma unroll
    for (unsigned p = 0; p < 32; ++p) {
      if (p & LSB) continue;
      const unsigned q = p ^ M2;
      const int s0 = __builtin_popcount((2u * p) & RHO) & 1;
      const int s1 = __builtin_popcount((2u * p + 1u) & RHO) & 1;
      const f32x2 Sp = mk2(s0 ? -sb : sb, s1 ? -sb : sb);
      const f32x2 Xp = v[p], Xq = v[q];
      v[p] = C * Xp - Sp * Xq;
      v[q] = C * Xq + Sp * Xp;   // sigma(l^MU) = -sigma(l)
    }
  } else if constexpr (M2 == 0) {  // MU==1: within-lane butterfly; RHO&1==1
#pragma unroll
    for (unsigned p = 0; p < 32; ++p) {
      const int s0 = __builtin_popcount((2u * p) & RHO) & 1;
      const f32x2 Sp = mk2(s0 ? -sb : sb, s0 ? sb : -sb);
      const f32x2 X = v[p];
      v[p] = C * X - Sp * mk2(X.y, X.x);
    }
  } else {  // MU odd, crosses lanes and registers
    constexpr unsigned LSB = M2 & (0u - M2);
#pragma unroll
    for (unsigned p = 0; p < 32; ++p) {
      if (p & LSB) continue;
      const unsigned q = p ^ M2;
      const int s0 = __builtin_popcount((2u * p) & RHO) & 1;
      const int s1 = __builtin_popcount((2u * p + 1u) & RHO) & 1;
      const f32x2 Sp = mk2(s0 ? -sb : sb, s1 ? -sb : sb);
      const f32x2 Xp = v[p], Xq = v[q];
      const f32x2 T = Sp * Xp;
      v[p] = C * Xp - Sp * mk2(Xq.y, Xq.x);
      v[q] = C * Xq + mk2(T.y, T.x);
    }
  }
}

__global__ __launch_bounds__(BLOCK, 2) void qnn_kernel(
    const float* __restrict__ x, const float* __restrict__ wts,
    float* __restrict__ out) {
  __shared__ float S[16384];  // 64 KB, reused: storage-1, storage-2, reduction
  f32x2* const F = (f32x2*)S;
  const unsigned t = threadIdx.x;
  const int b = blockIdx.x;

  f32x2 v2[32];

  // ---- Fill: x-encoding RY layer on |0..0> = product state, QA layout ----
  {
    float cxx[NQ], sxx[NQ];
#pragma unroll
    for (int w = 0; w < NQ; ++w) __sincosf(0.5f * x[b * NQ + w], &sxx[w], &cxx[w]);
    float pl = 1.0f;
#pragma unroll
    for (int bb = 0; bb < 8; ++bb) pl *= ((t >> bb) & 1) ? sxx[13 - bb] : cxx[13 - bb];
    v2[0] = mk2(pl * cxx[5], pl * sxx[5]);  // local bit0 (lane) = i8 = wire 5
#pragma unroll
    for (int k = 1; k < 6; ++k) {  // local bit k = i bit 8+k = wire 5-k
      const unsigned K = 1u << (k - 1);
      const f32x2 sk = mk2(sxx[5 - k], sxx[5 - k]);
      const f32x2 ck = mk2(cxx[5 - k], cxx[5 - k]);
#pragma unroll
      for (unsigned p = 0; p < 16; ++p) {
        if (p & ~(K - 1u)) continue;
        v2[p | K] = v2[p] * sk;
        v2[p] = v2[p] * ck;
      }
    }
  }

#define RUN_GATE(LM, G, BASEPAR)                                          \
  {                                                                       \
    float sn, cs;                                                         \
    __sincosf(0.5f * wts[G], &sn, &cs);                                   \
    const float sb =                                                      \
        (__builtin_popcount((BASEPAR) & SC.r[G]) & 1) ? -sn : sn;         \
    gate_pk<LM(SC.m[G]), LM(SC.r[G])>(v2, cs, sb);                        \
  }

  // ---------------- Phase QA: local bits {8..13}, lane = i8 ----------------
  {
    const unsigned base = t;  // i bits 0-7
    RUN_GATE(lmapA, QA_G[0], base) RUN_GATE(lmapA, QA_G[1], base)
    RUN_GATE(lmapA, QA_G[2], base) RUN_GATE(lmapA, QA_G[3], base)
    RUN_GATE(lmapA, QA_G[4], base) RUN_GATE(lmapA, QA_G[5], base)
    RUN_GATE(lmapA, QA_G[6], base) RUN_GATE(lmapA, QA_G[7], base)
    RUN_GATE(lmapA, QA_G[8], base) RUN_GATE(lmapA, QA_G[9], base)
#pragma unroll
    for (unsigned p = 0; p < 32; ++p) F[f2_QAw(t, p)] = v2[p];
  }
  __syncthreads();

  // ---------------- Phase QB: local bits {3..8}, lane = i8 ----------------
  {
    const unsigned base = (t & 7u) | ((t >> 3) << 9);  // i bits {0,1,2,9..13}
#pragma unroll
    for (unsigned p = 0; p < 32; ++p) v2[p] = F[f2_QBr(t, p)];
    RUN_GATE(lmapB, QB_G[0], base) RUN_GATE(lmapB, QB_G[1], base)
    RUN_GATE(lmapB, QB_G[2], base) RUN_GATE(lmapB, QB_G[3], base)
    RUN_GATE(lmapB, QB_G[4], base) RUN_GATE(lmapB, QB_G[5], base)
    RUN_GATE(lmapB, QB_G[6], base) RUN_GATE(lmapB, QB_G[7], base)
    RUN_GATE(lmapB, QB_G[8], base) RUN_GATE(lmapB, QB_G[9], base)
  }
  __syncthreads();  // all storage-1 reads done before overwriting as storage-2
  {
#pragma unroll
    for (unsigned p = 0; p < 32; ++p) {
      S[dw_QBw(t, p, 0)] = v2[p].x;
      S[dw_QBw(t, p, 1)] = v2[p].y;
    }
  }
  __syncthreads();

  // -------- Phase QC: local bits {0,1,2,3,12,13}, lane = i0 --------
  float ex[NQ];
  {
    const unsigned base = (((t >> 3) & 15u) << 4) | (((t >> 7) & 1u) << 8) | ((t & 7u) << 9);
#pragma unroll
    for (unsigned p = 0; p < 32; ++p) v2[p] = F[f2_QCr(t, p)];
    RUN_GATE(lmapC, QC_G[0], base) RUN_GATE(lmapC, QC_G[1], base)
    RUN_GATE(lmapC, QC_G[2], base) RUN_GATE(lmapC, QC_G[3], base)
    RUN_GATE(lmapC, QC_G[4], base) RUN_GATE(lmapC, QC_G[5], base)
    RUN_GATE(lmapC, QC_G[6], base) RUN_GATE(lmapC, QC_G[7], base)

    // ---- Measurement: q = v^2; WHT over local bits 1..5; bit0 folded ----
#pragma unroll
    for (unsigned p = 0; p < 32; ++p) v2[p] = v2[p] * v2[p];
#pragma unroll
    for (int k = 0; k < 5; ++k) {
      const unsigned K = 1u << k;
#pragma unroll
      for (unsigned p = 0; p < 32; ++p) {
        if (p & K) continue;
        const f32x2 A = v2[p], B = v2[p ^ K];
        v2[p] = A + B;
        v2[p ^ K] = A - B;
      }
    }
#pragma unroll
    for (int w = 0; w < NQ; ++w) {
      const unsigned ls = lmapC(SC.fr[w]);
      const f32x2 W = v2[ls >> 1];
      const float coef = (ls & 1u) ? (W.x - W.y) : (W.x + W.y);
      const int tf = __builtin_popcount(base & SC.fr[w]) & 1;
      ex[w] = tf ? -coef : coef;
    }
  }
  __syncthreads();  // all storage-2 reads done; S reusable for reduction

  // ---------------- block reduction ----------------
#pragma unroll
  for (int w = 0; w < NQ; ++w) {
#pragma unroll
    for (int off = 32; off > 0; off >>= 1) ex[w] += __shfl_xor(ex[w], off, 64);
  }
  const unsigned lane = t & 63u, wave = t >> 6;
  if (lane == 0) {
#pragma unroll
    for (int w = 0; w < NQ; ++w) S[wave * NQ + w] = ex[w];
  }
  __syncthreads();
  if (t < NQ) {
    out[b * NQ + t] = S[t] + S[NQ + t] + S[2 * NQ + t] + S[3 * NQ + t];
  }
#undef RUN_GATE
}

extern "C" void kernel_launch(void* const* d_in, const int* in_sizes, int n_in,
                              void* d_out, int out_size, void* d_ws, size_t ws_size,
                              hipStream_t stream) {
  const float* x = (const float*)d_in[0];        // (B, 14) fp32
  const float* weights = (const float*)d_in[1];  // (2, 14) fp32
  float* out = (float*)d_out;                    // (B, 14) fp32
  const int B = in_sizes[0] / NQ;
  qnn_kernel<<<B, BLOCK, 0, stream>>>(x, weights, out);
}

// Round 5
// 63.436 us; speedup vs baseline: 2.6917x; 1.0299x over previous
//
#include <hip/hip_runtime.h>

#define NQ 14
#define BLOCK 256
#define NG 28

typedef float f32x2 __attribute__((ext_vector_type(2)));
__device__ __forceinline__ f32x2 mk2(float a, float b) { f32x2 r; r.x = a; r.y = b; return r; }

// ---------------- compile-time schedule (lazy-CNOT folding) ----------------
struct Sched { unsigned m[NG]; unsigned r[NG]; unsigned fr[NQ]; };

constexpr Sched build_sched() {
  Sched sc{};
  unsigned col[NQ] = {}, rowinv[NQ] = {};
  for (int p = 0; p < NQ; ++p) { col[p] = 1u << p; rowinv[p] = 1u << p; }
  int g = 0;
  for (int l = 0; l < 2; ++l) {
    for (int w = 0; w < NQ; ++w) { int p = NQ - 1 - w; sc.m[g] = col[p]; sc.r[g] = rowinv[p]; ++g; }
    for (int w = 0; w < NQ; ++w) {
      int tgt = (w + 1) % NQ; int pc = NQ - 1 - w, pt = NQ - 1 - tgt;
      col[pc] ^= col[pt]; rowinv[pt] ^= rowinv[pc];
    }
  }
  for (int w = 0; w < NQ; ++w) sc.fr[w] = rowinv[NQ - 1 - w];
  return sc;
}
constexpr Sched SC = build_sched();

// Layer-0 weight RYs (gates 0..13) are ABSORBED into the product-state fill:
// RY(w0)RY(x)|0> = RY(x+w0)|0> per wire (all pre-CNOT). Remaining 14 gates:
constexpr int QA_G[4] = {15, 16, 17, 18};
constexpr int QB_G[5] = {19, 20, 21, 22, 23};
constexpr int QC_G[5] = {14, 24, 25, 26, 27};

// local-coordinate maps; local bit 0 == the f32x2 packed lane in each phase
constexpr unsigned lmapA(unsigned v) { return (v >> 8) & 63u; }                              // lane = i8
constexpr unsigned lmapB(unsigned v) { return ((v >> 8) & 1u) | (((v >> 3) & 31u) << 1); }   // lane = i8
constexpr unsigned lmapC(unsigned v) { return (v & 0xFu) | ((v >> 8) & 0x30u); }             // lane = i0

// ---------------- schedule legality (machine-checked) ----------------
constexpr bool sched_ok() {
  // absorbed gates: plain RY on wire g (m==r==single bit), applied pre-CNOT
  for (int g = 0; g < 14; ++g)
    if (SC.m[g] != (1u << (13 - g)) || SC.r[g] != (1u << (13 - g))) return false;
  const unsigned spanA = 0x3F00u, spanB = 0x01F8u, spanC = 0x300Fu;
  for (int k = 0; k < 4; ++k) {
    if (SC.m[QA_G[k]] & ~spanA) return false;
    if (!(__builtin_popcount(lmapA(SC.m[QA_G[k]]) & lmapA(SC.r[QA_G[k]])) & 1)) return false;
  }
  for (int k = 0; k < 5; ++k) {
    if (SC.m[QB_G[k]] & ~spanB) return false;
    if (!(__builtin_popcount(lmapB(SC.m[QB_G[k]]) & lmapB(SC.r[QB_G[k]])) & 1)) return false;
  }
  for (int k = 0; k < 5; ++k) {
    if (SC.m[QC_G[k]] & ~spanC) return false;
    if (!(__builtin_popcount(lmapC(SC.m[QC_G[k]]) & lmapC(SC.r[QC_G[k]])) & 1)) return false;
  }
  // execution order of the 14 remaining gates (absorbed 0..13 run first and
  // are also first in original order — no hoist across them)
  int ord[14] = {}; int n = 0;
  for (int k = 0; k < 4; ++k) ord[n++] = QA_G[k];
  for (int k = 0; k < 5; ++k) ord[n++] = QB_G[k];
  for (int k = 0; k < 5; ++k) ord[n++] = QC_G[k];
  for (int g = 14; g < NG; ++g) { int c = 0; for (int i = 0; i < 14; ++i) if (ord[i] == g) ++c; if (c != 1) return false; }
  for (int i = 0; i < 14; ++i)
    for (int j = i + 1; j < 14; ++j)
      if (ord[i] > ord[j]) {  // swapped vs original order -> must commute
        int a = ord[i], b = ord[j];
        if ((__builtin_popcount(SC.r[a] & SC.m[b]) & 1) != (__builtin_popcount(SC.r[b] & SC.m[a]) & 1)) return false;
      }
  return true;
}
static_assert(sched_ok(), "schedule invalid");

// ---------------- layouts: (thread,reg,lane) -> state index i ----------------
constexpr unsigned iQA(unsigned t, unsigned p, unsigned e) { return t | ((2u * p + e) << 8); }
constexpr unsigned iQB(unsigned t, unsigned p, unsigned e) { return (t & 7u) | (p << 3) | (e << 8) | ((t >> 3) << 9); }
constexpr unsigned iQC(unsigned T, unsigned p, unsigned e) {
  return e | ((p & 7u) << 1) | (((p >> 3) & 3u) << 12) | (((T >> 3) & 15u) << 4) | (((T >> 7) & 1u) << 8) | ((T & 7u) << 9);
}

// canonical storage maps (dword address as a function of state index i)
constexpr unsigned a1s(unsigned i) { unsigned tA = i & 255u, lA = i >> 8; return tA * 64u + (lA ^ ((tA & 15u) << 1)); }
constexpr unsigned Tof(unsigned i)  { return ((i >> 9) & 7u) | (((i >> 4) & 15u) << 3) | (((i >> 8) & 1u) << 7); }
constexpr unsigned lCof(unsigned i) { return (i & 15u) | (((i >> 12) & 3u) << 4); }
constexpr unsigned a2s(unsigned i) { unsigned T = Tof(i), l = lCof(i); return T * 64u + (l ^ ((T & 7u) << 2)); }

// ---- device-used address functions; same definitions evaluated in the
// exhaustive static_asserts below — no device/mirror drift possible. ----
__host__ __device__ constexpr unsigned f2_QAw(unsigned t, unsigned p) {
  return 32u * t + (p ^ (t & 15u));
}
__host__ __device__ constexpr unsigned f2_QBr(unsigned t, unsigned p) {
  return 256u * p + 32u * (t & 7u) + (((t >> 3) ^ (t & 7u)) ^ (8u * (p & 1u)));
}
__host__ __device__ constexpr unsigned dw_QBw(unsigned t, unsigned p, unsigned e) {
  const unsigned lc = (t & 7u) | (8u * (p & 1u)) | (16u * ((t >> 6) & 3u));
  return 64u * ((t >> 3) & 7u) + 512u * (p >> 1) + 8192u * e + (lc ^ (((t >> 3) & 7u) << 2));
}
__host__ __device__ constexpr unsigned f2_QCr(unsigned t, unsigned p) {
  return 32u * t + (p ^ ((t & 7u) << 1));   // swizzle hits p bits 1..3 (l bits 2..4)
}

constexpr bool basis_ok() {
  for (int mapi = 0; mapi < 3; ++mapi) {
    unsigned acc = 0;
    for (int k = 0; k < 14; ++k) {
      unsigned t = 0, p = 0, e = 0;
      if (k < 8) t = 1u << k; else if (k < 13) p = 1u << (k - 8); else e = 1;
      unsigned v = (mapi == 0) ? iQA(t, p, e) : (mapi == 1) ? iQB(t, p, e) : iQC(t, p, e);
      if (__builtin_popcount(v) != 1 || (acc & v)) return false;
      acc |= v;
    }
    if (acc != 0x3FFFu) return false;
  }
  return true;
}
static_assert(basis_ok(), "layout maps not bijective");

// exhaustive: every thread, register, lane; device formula == storage map
constexpr bool chk_addr(int pat, unsigned t0, unsigned t1) {
  for (unsigned t = t0; t < t1; ++t)
    for (unsigned p = 0; p < 32; ++p)
      for (unsigned e = 0; e < 2; ++e) {
        unsigned a = 0, b = 0;
        if (pat == 0) { a = 2u * f2_QAw(t, p) + e; b = a1s(iQA(t, p, e)); }
        if (pat == 1) { a = 2u * f2_QBr(t, p) + e; b = a1s(iQB(t, p, e)); }
        if (pat == 2) { a = dw_QBw(t, p, e);       b = a2s(iQB(t, p, e)); }
        if (pat == 3) { a = 2u * f2_QCr(t, p) + e; b = a2s(iQC(t, p, e)); }
        if (a != b || a >= 16384u) return false;
      }
  return true;
}
static_assert(chk_addr(0, 0, 128) && chk_addr(0, 128, 256), "QA write addr");
static_assert(chk_addr(1, 0, 128) && chk_addr(1, 128, 256), "QB read addr");
static_assert(chk_addr(2, 0, 128) && chk_addr(2, 128, 256), "QB write addr");
static_assert(chk_addr(3, 0, 128) && chk_addr(3, 128, 256), "QC read addr");

// ---------------- packed register butterfly ----------------
// v[l]' = c*v[l] - sigma(l)*sb*v[l^MU], sigma(l) = parity(l&RHO) ? -1 : +1,
// local 6-bit space, lane = bit 0; parity(MU&RHO)==1 asserted by sched_ok.
template <unsigned MU, unsigned RHO>
__device__ __forceinline__ void gate_pk(f32x2* v, const float cg, const float sb) {
  const f32x2 C = mk2(cg, cg);
  constexpr unsigned M2 = MU >> 1;
  constexpr bool ODD = (MU & 1u) != 0;
  if constexpr (!ODD) {
    constexpr unsigned LSB = M2 & (0u - M2);
#pragma unroll
    for (unsigned p = 0; p < 32; ++p) {
      if (p & LSB) continue;
      const unsigned q = p ^ M2;
      const int s0 = __builtin_popcount((2u * p) & RHO) & 1;
      const int s1 = __builtin_popcount((2u * p + 1u) & RHO) & 1;
      const f32x2 Sp = mk2(s0 ? -sb : sb, s1 ? -sb : sb);
      const f32x2 Xp = v[p], Xq = v[q];
      v[p] = C * Xp - Sp * Xq;
      v[q] = C * Xq + Sp * Xp;   // sigma(l^MU) = -sigma(l)
    }
  } else if constexpr (M2 == 0) {  // MU==1: within-lane butterfly; RHO&1==1
#pragma unroll
    for (unsigned p = 0; p < 32; ++p) {
      const int s0 = __builtin_popcount((2u * p) & RHO) & 1;
      const f32x2 Sp = mk2(s0 ? -sb : sb, s0 ? sb : -sb);
      const f32x2 X = v[p];
      v[p] = C * X - Sp * mk2(X.y, X.x);
    }
  } else {  // MU odd, crosses lanes and registers
    constexpr unsigned LSB = M2 & (0u - M2);
#pragma unroll
    for (unsigned p = 0; p < 32; ++p) {
      if (p & LSB) continue;
      const unsigned q = p ^ M2;
      const int s0 = __builtin_popcount((2u * p) & RHO) & 1;
      const int s1 = __builtin_popcount((2u * p + 1u) & RHO) & 1;
      const f32x2 Sp = mk2(s0 ? -sb : sb, s1 ? -sb : sb);
      const f32x2 Xp = v[p], Xq = v[q];
      const f32x2 T = Sp * Xp;
      v[p] = C * Xp - Sp * mk2(Xq.y, Xq.x);
      v[q] = C * Xq + mk2(T.y, T.x);
    }
  }
}

__global__ __launch_bounds__(BLOCK, 2) void qnn_kernel(
    const float* __restrict__ x, const float* __restrict__ wts,
    float* __restrict__ out) {
  __shared__ float S[16384];  // 64 KB, reused: storage-1, storage-2, reduction
  f32x2* const F = (f32x2*)S;
  const unsigned t = threadIdx.x & 255u;
  const int b = blockIdx.x;

  f32x2 v2[32];

  // ---- Fill: RY(x + weights[0]) layer on |0..0> = product state, QA layout ----
  {
    float cxx[NQ], sxx[NQ];
#pragma unroll
    for (int w = 0; w < NQ; ++w)
      __sincosf(0.5f * (x[b * NQ + w] + wts[w]), &sxx[w], &cxx[w]);
    float pl = 1.0f;
#pragma unroll
    for (int bb = 0; bb < 8; ++bb) pl *= ((t >> bb) & 1) ? sxx[13 - bb] : cxx[13 - bb];
    v2[0] = mk2(pl * cxx[5], pl * sxx[5]);  // local bit0 (lane) = i8 = wire 5
#pragma unroll
    for (int k = 1; k < 6; ++k) {  // local bit k = i bit 8+k = wire 5-k
      const unsigned K = 1u << (k - 1);
      const f32x2 sk = mk2(sxx[5 - k], sxx[5 - k]);
      const f32x2 ck = mk2(cxx[5 - k], cxx[5 - k]);
#pragma unroll
      for (unsigned p = 0; p < 16; ++p) {
        if (p & ~(K - 1u)) continue;
        v2[p | K] = v2[p] * sk;
        v2[p] = v2[p] * ck;
      }
    }
  }

#define RUN_GATE(LM, G, BASEPAR)                                          \
  {                                                                       \
    float sn, cs;                                                         \
    __sincosf(0.5f * wts[G], &sn, &cs);                                   \
    const float sb =                                                      \
        (__builtin_popcount((BASEPAR) & SC.r[G]) & 1) ? -sn : sn;         \
    gate_pk<LM(SC.m[G]), LM(SC.r[G])>(v2, cs, sb);                        \
  }

  // ---------------- Phase QA: local bits {8..13}, lane = i8 ----------------
  {
    const unsigned base = t;  // i bits 0-7
    RUN_GATE(lmapA, QA_G[0], base) RUN_GATE(lmapA, QA_G[1], base)
    RUN_GATE(lmapA, QA_G[2], base) RUN_GATE(lmapA, QA_G[3], base)
#pragma unroll
    for (unsigned p = 0; p < 32; ++p) F[f2_QAw(t, p)] = v2[p];
  }
  __syncthreads();

  // ---------------- Phase QB: local bits {3..8}, lane = i8 ----------------
  {
    const unsigned base = (t & 7u) | ((t >> 3) << 9);  // i bits {0,1,2,9..13}
#pragma unroll
    for (unsigned p = 0; p < 32; ++p) v2[p] = F[f2_QBr(t, p)];
    RUN_GATE(lmapB, QB_G[0], base) RUN_GATE(lmapB, QB_G[1], base)
    RUN_GATE(lmapB, QB_G[2], base) RUN_GATE(lmapB, QB_G[3], base)
    RUN_GATE(lmapB, QB_G[4], base)
  }
  __syncthreads();  // all storage-1 reads done before overwriting as storage-2
  {
#pragma unroll
    for (unsigned p = 0; p < 32; ++p) {
      S[dw_QBw(t, p, 0)] = v2[p].x;
      S[dw_QBw(t, p, 1)] = v2[p].y;
    }
  }
  __syncthreads();

  // -------- Phase QC: local bits {0,1,2,3,12,13}, lane = i0 --------
  float ex[NQ];
  {
    const unsigned base = (((t >> 3) & 15u) << 4) | (((t >> 7) & 1u) << 8) | ((t & 7u) << 9);
#pragma unroll
    for (unsigned p = 0; p < 32; ++p) v2[p] = F[f2_QCr(t, p)];
    RUN_GATE(lmapC, QC_G[0], base) RUN_GATE(lmapC, QC_G[1], base)
    RUN_GATE(lmapC, QC_G[2], base) RUN_GATE(lmapC, QC_G[3], base)
    RUN_GATE(lmapC, QC_G[4], base)

    // ---- Measurement: q = v^2; WHT over local bits 1..5; bit0 folded ----
#pragma unroll
    for (unsigned p = 0; p < 32; ++p) v2[p] = v2[p] * v2[p];
#pragma unroll
    for (int k = 0; k < 5; ++k) {
      const unsigned K = 1u << k;
#pragma unroll
      for (unsigned p = 0; p < 32; ++p) {
        if (p & K) continue;
        const f32x2 A = v2[p], B = v2[p ^ K];
        v2[p] = A + B;
        v2[p ^ K] = A - B;
      }
    }
#pragma unroll
    for (int w = 0; w < NQ; ++w) {
      const unsigned ls = lmapC(SC.fr[w]);
      const f32x2 W = v2[ls >> 1];
      const float coef = (ls & 1u) ? (W.x - W.y) : (W.x + W.y);
      const int tf = __builtin_popcount(base & SC.fr[w]) & 1;
      ex[w] = tf ? -coef : coef;
    }
  }
  __syncthreads();  // all storage-2 reads done; S reusable for reduction

  // ---------------- block reduction ----------------
#pragma unroll
  for (int w = 0; w < NQ; ++w) {
#pragma unroll
    for (int off = 32; off > 0; off >>= 1) ex[w] += __shfl_xor(ex[w], off, 64);
  }
  const unsigned lane = t & 63u, wave = t >> 6;
  if (lane == 0) {
#pragma unroll
    for (int w = 0; w < NQ; ++w) S[wave * NQ + w] = ex[w];
  }
  __syncthreads();
  if (t < NQ) {
    out[b * NQ + t] = S[t] + S[NQ + t] + S[2 * NQ + t] + S[3 * NQ + t];
  }
#undef RUN_GATE
}

extern "C" void kernel_launch(void* const* d_in, const int* in_sizes, int n_in,
                              void* d_out, int out_size, void* d_ws, size_t ws_size,
                              hipStream_t stream) {
  const float* x = (const float*)d_in[0];        // (B, 14) fp32
  const float* weights = (const float*)d_in[1];  // (2, 14) fp32
  float* out = (float*)d_out;                    // (B, 14) fp32
  const int B = in_sizes[0] / NQ;
  qnn_kernel<<<B, BLOCK, 0, stream>>>(x, weights, out);
}